// Round 6
// baseline (130.668 us; speedup 1.0000x reference)
//
#include <hip/hip_runtime.h>
#include <stdint.h>

#define ALPHA 0.2f
#define LOG2E 1.4426950408889634f

typedef unsigned short u16;
typedef short s16x8 __attribute__((ext_vector_type(8)));   // 8 bf16 as shorts
typedef float f32x4 __attribute__((ext_vector_type(4)));

union BF8 { s16x8 v; uint32_t u[4]; u16 s[8]; uint4 q; };

static __device__ __forceinline__ float bf2f(u16 u) {
  union { uint32_t i; float f; } c; c.i = ((uint32_t)u) << 16; return c.f;
}
// round-to-nearest pack of two f32 -> packed bf16x2
static __device__ __forceinline__ uint32_t pk2bf(float lo, float hi) {
  uint32_t ul = __float_as_uint(lo) + 0x8000u;
  uint32_t uh = __float_as_uint(hi) + 0x8000u;
  return (ul >> 16) | (uh & 0xffff0000u);
}

// async global->LDS, 16B per lane; lds dest must be wave-uniform base
static __device__ __forceinline__ void gl2lds16(const void* g, void* l) {
  __builtin_amdgcn_global_load_lds(
      (const __attribute__((address_space(1))) uint32_t*)g,
      (__attribute__((address_space(3))) uint32_t*)l, 16, 0, 0);
}

// ------------- fallback: ws too small -> zero output (diagnostic) --------
__global__ __launch_bounds__(256) void k_zero(uint32_t* __restrict__ out, int n32) {
  int gid = blockIdx.x * 256 + threadIdx.x;
  if (gid < n32) out[gid] = 0u;
}

// ---------------- kernel 1 (fused): adj-pack + dtype flag + Wh GEMM -------
// blocks 0..2047: pack adj -> bitmask (block 0 also writes dtype flag).
// blocks 2048..2559: WhT = (h@W)^T (32 rows each) + e_src/e_dst.
// WhT: [8][128][2048] bf16 ; eS/eD: [8][2048] f32 (pre-scaled by log2e)
__global__ __launch_bounds__(256) void k_prep(
    const int* __restrict__ adj, uint32_t* __restrict__ bits,
    const void* __restrict__ hV, const void* __restrict__ WgV,
    const void* __restrict__ aSrcV, const void* __restrict__ aDstV,
    int* __restrict__ flag,
    u16* __restrict__ WhT, float* __restrict__ eS, float* __restrict__ eD) {
  __shared__ __align__(16) char smemRaw[34816];   // WT bf16[128][136] / f32 tile[32][130]
  __shared__ float aS[128], aD[128];
  __shared__ float ePs[2][32][2];                 // [src/dst][row][colhalf]

  const int tid = threadIdx.x;
  const int bk = blockIdx.x;
  const int lane = tid & 63;

  if (bk < 2048) {            // ---------------- pack role ----------------
    int base = bk * 256 + tid;
#pragma unroll
    for (int it = 0; it < 8; ++it) {
      int gid = base + it * (2048 * 256);
      unsigned long long m = __ballot(adj[gid] != 0);
      if ((tid & 63) == 0)
        *(unsigned long long*)(&bits[gid >> 5]) = m;
    }
    if (bk == 0 && tid < 64) {   // dtype vote (1=bf16, 0=fp32)
      u16 v = ((const u16*)hV)[2 * tid];
      int e = (v >> 7) & 0xff;
      unsigned long long dm = __ballot(e >= 100 && e <= 140);
      if (tid == 0) flag[0] = (__popcll(dm) >= 48) ? 1 : 0;
    }
    return;
  }

  // ---------------- wh role: 32 rows per block ----------------
  u16*   WT   = (u16*)smemRaw;
  float* tile = (float*)smemRaw;
  const int whid = bk - 2048;
  const int mb = whid * 32;

  // wave-local dtype vote (identical result in every wave; no barrier)
  int isBf;
  {
    u16 v = ((const u16*)hV)[2 * lane];
    int e = (v >> 7) & 0xff;
    unsigned long long dm = __ballot(e >= 100 && e <= 140);
    isBf = (__popcll(dm) >= 48) ? 1 : 0;
  }

  if (isBf) {
    const u16* Wg = (const u16*)WgV;
    for (int it = 0; it < 8; ++it) {
      int idx = tid + it * 256;
      int k = idx >> 4, c0 = (idx & 15) * 8;
      uint4 w4 = *(const uint4*)(Wg + (k << 7) + c0);
      u16* wsv = (u16*)&w4;
#pragma unroll
      for (int e = 0; e < 8; ++e) WT[(c0 + e) * 136 + k] = wsv[e];
    }
    if (tid < 128) aS[tid] = bf2f(((const u16*)aSrcV)[tid]);
    else           aD[tid - 128] = bf2f(((const u16*)aDstV)[tid - 128]);
  } else {
    const float* Wg = (const float*)WgV;
    for (int it = 0; it < 8; ++it) {
      int idx = tid + it * 256;
      int k = idx >> 4, c0 = (idx & 15) * 8;
      float4 w0 = *(const float4*)(Wg + (k << 7) + c0);
      float4 w1 = *(const float4*)(Wg + (k << 7) + c0 + 4);
      float wf[8] = {w0.x, w0.y, w0.z, w0.w, w1.x, w1.y, w1.z, w1.w};
#pragma unroll
      for (int e = 0; e < 8; ++e)
        WT[(c0 + e) * 136 + k] = (u16)((__float_as_uint(wf[e]) + 0x8000u) >> 16);
    }
    if (tid < 128) aS[tid] = ((const float*)aSrcV)[tid];
    else           aD[tid - 128] = ((const float*)aDstV)[tid - 128];
  }
  __syncthreads();

  const int wv = tid >> 6, ln = lane & 15, quad = lane >> 4;
  const int rh = wv & 1, ch = wv >> 1;       // row-half (16), col-half (64)
  const int row = mb + rh * 16 + ln;

  f32x4 acc[4];
#pragma unroll
  for (int t = 0; t < 4; ++t) acc[t] = (f32x4){0.f, 0.f, 0.f, 0.f};

  if (isBf) {
    const u16* h = (const u16*)hV;
#pragma unroll
    for (int ks = 0; ks < 4; ++ks) {
      s16x8 af = *(const s16x8*)(h + (row << 7) + ks * 32 + quad * 8);
#pragma unroll
      for (int t = 0; t < 4; ++t) {
        s16x8 bfg = *(const s16x8*)(&WT[(ch * 64 + t * 16 + ln) * 136 + ks * 32 + quad * 8]);
        acc[t] = __builtin_amdgcn_mfma_f32_16x16x32_bf16(af, bfg, acc[t], 0, 0, 0);
      }
    }
  } else {
    const float* h = (const float*)hV;
#pragma unroll
    for (int ks = 0; ks < 4; ++ks) {
      float4 a0 = *(const float4*)(h + (row << 7) + ks * 32 + quad * 8);
      float4 a1 = *(const float4*)(h + (row << 7) + ks * 32 + quad * 8 + 4);
      BF8 af;
      af.u[0] = pk2bf(a0.x, a0.y);
      af.u[1] = pk2bf(a0.z, a0.w);
      af.u[2] = pk2bf(a1.x, a1.y);
      af.u[3] = pk2bf(a1.z, a1.w);
#pragma unroll
      for (int t = 0; t < 4; ++t) {
        s16x8 bfg = *(const s16x8*)(&WT[(ch * 64 + t * 16 + ln) * 136 + ks * 32 + quad * 8]);
        acc[t] = __builtin_amdgcn_mfma_f32_16x16x32_bf16(af.v, bfg, acc[t], 0, 0, 0);
      }
    }
  }

  // in-register e_src/e_dst partials over this wave's 64 cols
  {
    float pS[4] = {0.f, 0.f, 0.f, 0.f}, pD[4] = {0.f, 0.f, 0.f, 0.f};
#pragma unroll
    for (int t = 0; t < 4; ++t) {
      float av = aS[ch * 64 + t * 16 + ln];
      float dv = aD[ch * 64 + t * 16 + ln];
#pragma unroll
      for (int r = 0; r < 4; ++r) { pS[r] += acc[t][r] * av; pD[r] += acc[t][r] * dv; }
    }
#pragma unroll
    for (int m = 1; m < 16; m <<= 1) {
#pragma unroll
      for (int r = 0; r < 4; ++r) {
        pS[r] += __shfl_xor(pS[r], m);
        pD[r] += __shfl_xor(pD[r], m);
      }
    }
    if (ln == 0) {
#pragma unroll
      for (int r = 0; r < 4; ++r) {
        ePs[0][rh * 16 + quad * 4 + r][ch] = pS[r];
        ePs[1][rh * 16 + quad * 4 + r][ch] = pD[r];
      }
    }
  }
  __syncthreads();                                 // WT reads done; reuse as tile

  // D layout: row = quad*4+r, col = t*16+ln
#pragma unroll
  for (int t = 0; t < 4; ++t)
#pragma unroll
    for (int r = 0; r < 4; ++r)
      tile[(rh * 16 + quad * 4 + r) * 130 + ch * 64 + t * 16 + ln] = acc[t][r];
  __syncthreads();

  if (tid < 64) {
    int r = tid & 31, which = tid >> 5;
    float sum = ePs[which][r][0] + ePs[which][r][1];
    int m = mb + r, b = m >> 11, n = m & 2047;
    (which ? eD : eS)[(b << 11) + n] = sum * LOG2E;
  }

  // write WhT[b][d][n] (transposed bf16), 32B per thread
  {
    int d = tid >> 1, half = tid & 1;
    int n0 = mb & 2047, b = mb >> 11;
    uint32_t pk[8];
#pragma unroll
    for (int q = 0; q < 8; ++q) {
      float v0 = tile[(half * 16 + 2 * q) * 130 + d];
      float v1 = tile[(half * 16 + 2 * q + 1) * 130 + d];
      pk[q] = pk2bf(v0, v1);
    }
    uint4* dst = (uint4*)(WhT + (size_t)((b << 7) + d) * 2048 + n0 + half * 16);
    dst[0] = make_uint4(pk[0], pk[1], pk[2], pk[3]);
    dst[1] = make_uint4(pk[4], pk[5], pk[6], pk[7]);
  }
}

// ---------------- kernel 2: masked softmax(rank-1 logits) @ Wh, j-split ---
// UNCHANGED from round 5 (best measured attn structure).
__global__ __launch_bounds__(512, 8) void k_attn(
    const u16* __restrict__ WhT, const float* __restrict__ eSrc,
    const float* __restrict__ eDst, const uint32_t* __restrict__ adjBits,
    float* __restrict__ numP, float* __restrict__ denP) {
  __shared__ __align__(16) u16 bufB[2][8192];   // 2 x 16KB  [128 d][64 j]
  __shared__ __align__(16) u16 bufP[2][2048];   // 2 x 4KB   [32 i][64 j]

  const int tid = threadIdx.x;
  // XCD swizzle: 1024 % 8 == 0, b == XCD id -> each XCD L2 holds one WhT[b]
  const int bid = (blockIdx.x & 7) * 128 + (blockIdx.x >> 3);
  const int b = bid >> 7, rest = bid & 127;
  const int jq = rest & 1, ig = rest >> 1;
  const int i0 = ig * 32;

  const int w = tid >> 6, l = tid & 63;
  const int ln = l & 15, quad = l >> 4;
  const int s = w & 1, dh = w >> 1;

  // ---- staging constants (B tile), round-2 swizzle, + jq column offset ----
  const int gsrc = (l & 7) ^ ((l >> 3) & 7);
  const u16* whtB = WhT + ((size_t)b << 18);
  const u16* srcB = whtB + (size_t)(w * 8 + (l >> 3)) * 2048 + jq * 1024 + gsrc * 8;

  // ---- P producer constants (4 exps/thread/step, cooperative) ----
  const int prow = tid >> 4, hg = tid & 15;       // row 0..31, 4-j group 0..15
  const float sSp = eSrc[(b << 11) + i0 + prow];
  const float* eDb = eDst + (b << 11) + jq * 1024 + hg * 4;
  const uint32_t* adjB = adjBits + (size_t)(i0 + prow) * 64 + jq * 32 + (hg >> 3);
  const int pOff = prow * 128 + ((hg ^ ((prow & 7) << 1)) * 8);   // bytes
  float dsum = 0.f;

  // ---- consumer LDS offsets (bytes), unchanged from round 2 ----
  const int aOff0 = (s * 16 + ln) * 128 + (((0 * 4 + quad) ^ (ln & 7)) * 16);
  const int aOff1 = (s * 16 + ln) * 128 + (((1 * 4 + quad) ^ (ln & 7)) * 16);
  const int bOff00 = (dh * 32 + 0 * 16 + ln) * 128 + (((0 * 4 + quad) ^ (ln & 7)) * 16);
  const int bOff10 = (dh * 32 + 1 * 16 + ln) * 128 + (((0 * 4 + quad) ^ (ln & 7)) * 16);
  const int bOff01 = (dh * 32 + 0 * 16 + ln) * 128 + (((1 * 4 + quad) ^ (ln & 7)) * 16);
  const int bOff11 = (dh * 32 + 1 * 16 + ln) * 128 + (((1 * 4 + quad) ^ (ln & 7)) * 16);

  f32x4 acc0 = (f32x4){0.f, 0.f, 0.f, 0.f};
  f32x4 acc1 = (f32x4){0.f, 0.f, 0.f, 0.f};

  // produce P tile, accumulating the bf16-rounded row-sum (den partial)
#define PPROD(dv, aw, pdst) {                                                 \
    uint32_t nib = ((aw) >> ((hg & 7) * 4)) & 0xfu;                           \
    float x0 = sSp + (dv)[0], x1 = sSp + (dv)[1];                             \
    float x2 = sSp + (dv)[2], x3 = sSp + (dv)[3];                             \
    float p0 = exp2f(__builtin_amdgcn_fmed3f(x0, ALPHA * x0, 80.f));          \
    float p1 = exp2f(__builtin_amdgcn_fmed3f(x1, ALPHA * x1, 80.f));          \
    float p2 = exp2f(__builtin_amdgcn_fmed3f(x2, ALPHA * x2, 80.f));          \
    float p3 = exp2f(__builtin_amdgcn_fmed3f(x3, ALPHA * x3, 80.f));          \
    p0 = (nib & 1u) ? p0 : 0.f;                                               \
    p1 = (nib & 2u) ? p1 : 0.f;                                               \
    p2 = (nib & 4u) ? p2 : 0.f;                                               \
    p3 = (nib & 8u) ? p3 : 0.f;                                               \
    uint32_t w0 = pk2bf(p0, p1), w1 = pk2bf(p2, p3);                          \
    dsum += __uint_as_float(w0 << 16) + __uint_as_float(w0 & 0xffff0000u)     \
          + __uint_as_float(w1 << 16) + __uint_as_float(w1 & 0xffff0000u);    \
    *(uint2*)((char*)(pdst) + pOff) = make_uint2(w0, w1);                     \
  }

#define CONSUME(pPc, pBc) {                                                   \
    s16x8 af0 = *(const s16x8*)((const char*)(pPc) + aOff0);                  \
    s16x8 af1 = *(const s16x8*)((const char*)(pPc) + aOff1);                  \
    s16x8 b00 = *(const s16x8*)((const char*)(pBc) + bOff00);                 \
    s16x8 b10 = *(const s16x8*)((const char*)(pBc) + bOff10);                 \
    s16x8 b01 = *(const s16x8*)((const char*)(pBc) + bOff01);                 \
    s16x8 b11 = *(const s16x8*)((const char*)(pBc) + bOff11);                 \
    __builtin_amdgcn_s_setprio(1);                                            \
    acc0 = __builtin_amdgcn_mfma_f32_16x16x32_bf16(af0, b00, acc0, 0, 0, 0);  \
    acc1 = __builtin_amdgcn_mfma_f32_16x16x32_bf16(af0, b10, acc1, 0, 0, 0);  \
    acc0 = __builtin_amdgcn_mfma_f32_16x16x32_bf16(af1, b01, acc0, 0, 0, 0);  \
    acc1 = __builtin_amdgcn_mfma_f32_16x16x32_bf16(af1, b11, acc1, 0, 0, 0);  \
    __builtin_amdgcn_s_setprio(0);                                            \
  }

  u16 *bBc = bufB[0], *bBn = bufB[1];
  u16 *bPc = bufP[0], *bPn = bufP[1];

  // ---- prologue: produce P0, prefetch I1 into regs, stage B0 ----
  f32x4 dv = *(const f32x4*)(eDb);
  uint32_t aw = adjB[0];
  PPROD(dv, aw, bPc);
  dv = *(const f32x4*)(eDb + 64);
  aw = adjB[2];
  gl2lds16(srcB, bBc + w * 512);
  gl2lds16(srcB + 131072, bBc + 4096 + w * 512);
  __syncthreads();

  for (int t = 0; t < 16; ++t) {
    if (t + 1 < 16) {
      // stage B(t+1)
      gl2lds16(srcB + (size_t)(t + 1) * 64, bBn + w * 512);
      gl2lds16(srcB + (size_t)(t + 1) * 64 + 131072, bBn + 4096 + w * 512);
      // produce P(t+1) from prefetched regs
      PPROD(dv, aw, bPn);
      if (t + 2 < 16) {            // prefetch I(t+2)
        dv = *(const f32x4*)(eDb + (t + 2) * 64);
        aw = adjB[(t + 2) * 2];
      }
    }
    CONSUME(bPc, bBc);
    __syncthreads();               // next B staged + next P written; cur reads done
    u16* tb = bBc; bBc = bBn; bBn = tb;
    u16* tp = bPc; bPc = bPn; bPn = tp;
  }

  // ---- epilogue: write f32 partial numerator + denominator ----
  {
    // den: reduce dsum across the 16 hg-lanes of each row
#pragma unroll
    for (int m = 1; m < 16; m <<= 1) dsum += __shfl_xor(dsum, m);
    if ((tid & 15) == 0)
      denP[jq * 16384 + (b << 11) + i0 + prow] = dsum;

    float* np = numP + ((size_t)jq << 21)
              + ((size_t)((b << 11) + i0 + s * 16 + quad * 4) << 7)
              + dh * 32 + ln;
#pragma unroll
    for (int r = 0; r < 4; ++r) {
      np[r * 128 + 0]  = acc0[r];
      np[r * 128 + 16] = acc1[r];
    }
  }
#undef PPROD
#undef CONSUME
}

// ---------------- kernel 3: merge j-halves, normalize, cast --------------
__global__ __launch_bounds__(256) void k_merge(
    const float* __restrict__ numP, const float* __restrict__ denP,
    const int* __restrict__ flag, void* __restrict__ outV) {
  const int gid = blockIdx.x * 256 + threadIdx.x;
  const int e0 = gid * 8;           // 8 floats, same output row (128 | 8)
  const int row = e0 >> 7;

  f32x4 a0 = *(const f32x4*)(numP + e0);
  f32x4 a1 = *(const f32x4*)(numP + e0 + 4);
  f32x4 b0 = *(const f32x4*)(numP + (1 << 21) + e0);
  f32x4 b1 = *(const f32x4*)(numP + (1 << 21) + e0 + 4);
  float ds = denP[row] + denP[16384 + row];
  float inv = 1.0f / fmaxf(ds, 1e-37f);

  f32x4 v0 = (a0 + b0) * inv;
  f32x4 v1 = (a1 + b1) * inv;

  if (*flag) {
    uint4 pk = make_uint4(pk2bf(v0[0], v0[1]), pk2bf(v0[2], v0[3]),
                          pk2bf(v1[0], v1[1]), pk2bf(v1[2], v1[3]));
    *(uint4*)((u16*)outV + e0) = pk;
  } else {
    *(f32x4*)((float*)outV + e0) = v0;
    *(f32x4*)((float*)outV + e0 + 4) = v1;
  }
}

extern "C" void kernel_launch(void* const* d_in, const int* in_sizes, int n_in,
                              void* d_out, int out_size, void* d_ws, size_t ws_size,
                              hipStream_t stream) {
  const void* h   = d_in[0];
  const int* adj  = (const int*)d_in[1];
  const void* Wg  = d_in[2];
  const void* aS  = d_in[3];
  const void* aD  = d_in[4];

  const size_t OFF_ES   = (size_t)4 << 20;               // 4 MB WhT
  const size_t OFF_ED   = OFF_ES + (64 << 10);
  const size_t OFF_BITS = OFF_ED + (64 << 10);
  const size_t OFF_FLAG = OFF_BITS + (512 << 10);
  const size_t OFF_NUM  = (size_t)5 << 20;               // 2 x 8 MB f32 partial num
  const size_t OFF_DEN  = (size_t)21 << 20;              // 2 x 64 KB f32 partial den
  const size_t NEEDED   = OFF_DEN + (128 << 10);

  if (ws_size < NEEDED) {
    int n32 = out_size / 2;
    k_zero<<<(n32 + 255) / 256, 256, 0, stream>>>((uint32_t*)d_out, n32);
    return;
  }

  char* ws = (char*)d_ws;
  u16* WhT      = (u16*)ws;
  float* eSp    = (float*)(ws + OFF_ES);
  float* eDp    = (float*)(ws + OFF_ED);
  uint32_t* bit = (uint32_t*)(ws + OFF_BITS);
  int* flag     = (int*)(ws + OFF_FLAG);
  float* numP   = (float*)(ws + OFF_NUM);
  float* denP   = (float*)(ws + OFF_DEN);

  k_prep<<<2560, 256, 0, stream>>>(adj, bit, h, Wg, aS, aD, flag, WhT, eSp, eDp);
  k_attn<<<1024, 512, 0, stream>>>(WhT, eSp, eDp, bit, numP, denP);
  k_merge<<<1024, 256, 0, stream>>>(numP, denP, flag, d_out);
}

// Round 7
// 127.492 us; speedup vs baseline: 1.0249x; 1.0249x over previous
//
#include <hip/hip_runtime.h>
#include <stdint.h>

#define ALPHA 0.2f
#define LOG2E 1.4426950408889634f

typedef unsigned short u16;
typedef short s16x8 __attribute__((ext_vector_type(8)));   // 8 bf16 as shorts
typedef float f32x4 __attribute__((ext_vector_type(4)));

union BF8 { s16x8 v; uint32_t u[4]; u16 s[8]; uint4 q; };

static __device__ __forceinline__ float bf2f(u16 u) {
  union { uint32_t i; float f; } c; c.i = ((uint32_t)u) << 16; return c.f;
}
// round-to-nearest pack of two f32 -> packed bf16x2
static __device__ __forceinline__ uint32_t pk2bf(float lo, float hi) {
  uint32_t ul = __float_as_uint(lo) + 0x8000u;
  uint32_t uh = __float_as_uint(hi) + 0x8000u;
  return (ul >> 16) | (uh & 0xffff0000u);
}

// async global->LDS, 16B per lane; lds dest = wave-uniform base + lane*16
static __device__ __forceinline__ void gl2lds16(const void* g, void* l) {
  __builtin_amdgcn_global_load_lds(
      (const __attribute__((address_space(1))) uint32_t*)g,
      (__attribute__((address_space(3))) uint32_t*)l, 16, 0, 0);
}

// ------------- fallback: ws too small -> zero output (diagnostic) --------
__global__ __launch_bounds__(256) void k_zero(uint32_t* __restrict__ out, int n32) {
  int gid = blockIdx.x * 256 + threadIdx.x;
  if (gid < n32) out[gid] = 0u;
}

// ---------------- kernel 0: pack adj -> bitmask; block 0 also detects dtype
__global__ __launch_bounds__(256) void k_pack_adj(const int* __restrict__ adj,
                                                  uint32_t* __restrict__ bits,
                                                  const u16* __restrict__ h,
                                                  int* __restrict__ flag) {
  int tid = threadIdx.x;
  int base = blockIdx.x * 256 + tid;
#pragma unroll
  for (int it = 0; it < 8; ++it) {
    int gid = base + it * (2048 * 256);
    unsigned long long m = __ballot(adj[gid] != 0);
    if ((tid & 63) == 0)
      *(unsigned long long*)(&bits[gid >> 5]) = m;
  }
  if (blockIdx.x == 0 && tid < 64) {   // wave 0: dtype vote (1=bf16, 0=fp32)
    u16 v = h[2 * tid];
    int e = (v >> 7) & 0xff;
    unsigned long long dm = __ballot(e >= 100 && e <= 140);
    if (tid == 0) flag[0] = (__popcll(dm) >= 48) ? 1 : 0;
  }
}

// ---------------- kernel 1: WhT = (h@W)^T per batch, + e_src/e_dst --------
// WhT: [8][128][2048] bf16 ; eS/eD: [8][2048] f32 (pre-scaled by log2e)
__global__ __launch_bounds__(256) void k_wh(
    const void* __restrict__ hV, const void* __restrict__ WgV,
    const void* __restrict__ aSrcV, const void* __restrict__ aDstV,
    const int* __restrict__ flag,
    u16* __restrict__ WhT, float* __restrict__ eS, float* __restrict__ eD) {
  __shared__ __align__(16) char smemRaw[34816];    // WT bf16[128][136] then f32 tile[64][130]
  u16*   WT   = (u16*)smemRaw;
  float* tile = (float*)smemRaw;
  __shared__ float aS[128], aD[128];

  const int tid = threadIdx.x;
  const int mb = blockIdx.x * 64;
  const int isBf = *flag;

  if (isBf) {
    const u16* Wg = (const u16*)WgV;
    for (int it = 0; it < 8; ++it) {
      int idx = tid + it * 256;
      int k = idx >> 4, c0 = (idx & 15) * 8;
      uint4 w4 = *(const uint4*)(Wg + (k << 7) + c0);
      u16* wsv = (u16*)&w4;
#pragma unroll
      for (int e = 0; e < 8; ++e) WT[(c0 + e) * 136 + k] = wsv[e];
    }
    if (tid < 128) aS[tid] = bf2f(((const u16*)aSrcV)[tid]);
    else           aD[tid - 128] = bf2f(((const u16*)aDstV)[tid - 128]);
  } else {
    const float* Wg = (const float*)WgV;
    for (int it = 0; it < 8; ++it) {
      int idx = tid + it * 256;
      int k = idx >> 4, c0 = (idx & 15) * 8;
      float4 w0 = *(const float4*)(Wg + (k << 7) + c0);
      float4 w1 = *(const float4*)(Wg + (k << 7) + c0 + 4);
      float wf[8] = {w0.x, w0.y, w0.z, w0.w, w1.x, w1.y, w1.z, w1.w};
#pragma unroll
      for (int e = 0; e < 8; ++e)
        WT[(c0 + e) * 136 + k] = (u16)((__float_as_uint(wf[e]) + 0x8000u) >> 16);
    }
    if (tid < 128) aS[tid] = ((const float*)aSrcV)[tid];
    else           aD[tid - 128] = ((const float*)aDstV)[tid - 128];
  }
  __syncthreads();

  const int wv = tid >> 6, lane = tid & 63, ln = lane & 15, quad = lane >> 4;
  const int row = mb + wv * 16 + ln;

  f32x4 acc[8];
#pragma unroll
  for (int t = 0; t < 8; ++t) acc[t] = (f32x4){0.f, 0.f, 0.f, 0.f};

  if (isBf) {
    const u16* h = (const u16*)hV;
#pragma unroll
    for (int ks = 0; ks < 4; ++ks) {
      s16x8 af = *(const s16x8*)(h + (row << 7) + ks * 32 + quad * 8);
#pragma unroll
      for (int t = 0; t < 8; ++t) {
        s16x8 bfg = *(const s16x8*)(&WT[(t * 16 + ln) * 136 + ks * 32 + quad * 8]);
        acc[t] = __builtin_amdgcn_mfma_f32_16x16x32_bf16(af, bfg, acc[t], 0, 0, 0);
      }
    }
  } else {
    const float* h = (const float*)hV;
#pragma unroll
    for (int ks = 0; ks < 4; ++ks) {
      float4 a0 = *(const float4*)(h + (row << 7) + ks * 32 + quad * 8);
      float4 a1 = *(const float4*)(h + (row << 7) + ks * 32 + quad * 8 + 4);
      BF8 af;
      af.u[0] = pk2bf(a0.x, a0.y);
      af.u[1] = pk2bf(a0.z, a0.w);
      af.u[2] = pk2bf(a1.x, a1.y);
      af.u[3] = pk2bf(a1.z, a1.w);
#pragma unroll
      for (int t = 0; t < 8; ++t) {
        s16x8 bfg = *(const s16x8*)(&WT[(t * 16 + ln) * 136 + ks * 32 + quad * 8]);
        acc[t] = __builtin_amdgcn_mfma_f32_16x16x32_bf16(af.v, bfg, acc[t], 0, 0, 0);
      }
    }
  }
  __syncthreads();                                   // done with WT; reuse as tile

  // D layout: row = quad*4+r, col = t*16+ln
#pragma unroll
  for (int t = 0; t < 8; ++t)
#pragma unroll
    for (int r = 0; r < 4; ++r)
      tile[(wv * 16 + quad * 4 + r) * 130 + t * 16 + ln] = acc[t][r];
  __syncthreads();

  if (tid < 128) {
    int r = tid & 63, grp = tid >> 6;
    const float* a = grp ? aD : aS;
    float sum = 0.f;
#pragma unroll 4
    for (int d = 0; d < 128; ++d) sum += tile[r * 130 + d] * a[d];
    int m = mb + r, b = m >> 11, n = m & 2047;
    (grp ? eD : eS)[(b << 11) + n] = sum * LOG2E;
  }

  // write WhT[b][d][n] (transposed bf16), 64B per thread
  {
    int d = tid >> 1, half = tid & 1;
    int n0 = mb & 2047, b = mb >> 11;
    uint32_t pk[16];
#pragma unroll
    for (int qq = 0; qq < 16; ++qq) {
      float v0 = tile[(half * 32 + 2 * qq) * 130 + d];
      float v1 = tile[(half * 32 + 2 * qq + 1) * 130 + d];
      pk[qq] = pk2bf(v0, v1);
    }
    uint4* dst = (uint4*)(WhT + (size_t)((b << 7) + d) * 2048 + n0 + half * 32);
#pragma unroll
    for (int c = 0; c < 4; ++c)
      dst[c] = make_uint4(pk[c * 4], pk[c * 4 + 1], pk[c * 4 + 2], pk[c * 4 + 3]);
  }
}

// ---------------- kernel 2: masked softmax(rank-1 logits) @ Wh ------------
// 256-thread blocks (4 waves), 20KB LDS -> 8 blocks/CU = 32 waves/CU (100%
// occupancy; all 2048 blocks resident). grid 2048 = b(8) x ig(64, 32 rows)
// x jq(4, 512 j each -> 16 steps of 32 j). Same proven pipeline as R5:
// coop P production into LDS, 2-deep gl2lds dbuf on B, one barrier/step.
// Swizzle: 16B granule ^= (row&3) within 64B rows, applied on BOTH the
// pre-swizzled global source (staging) and the read offsets (involution).
__global__ __launch_bounds__(256, 8) void k_attn(
    const u16* __restrict__ WhT, const float* __restrict__ eSrc,
    const float* __restrict__ eDst, const uint32_t* __restrict__ adjBits,
    float* __restrict__ numP, float* __restrict__ denP) {
  __shared__ __align__(16) u16 bufB[2][4096];   // 2 x 8KB  [128 d][32 j]
  __shared__ __align__(16) u16 bufP[2][1024];   // 2 x 2KB  [32 i][32 j]

  const int tid = threadIdx.x;
  // XCD swizzle: 2048 % 8 == 0, b == XCD id -> each XCD L2 holds one WhT[b]
  const int bid = (blockIdx.x & 7) * 256 + (blockIdx.x >> 3);
  const int b = bid >> 8, rest = bid & 255;
  const int jq = rest & 3, ig = rest >> 2;
  const int i0 = ig * 32;

  const int w = tid >> 6, l = tid & 63;
  const int ln = l & 15, quad = l >> 4;
  const int s = w & 1, dh = w >> 1;

  // ---- staging constants: wave w call c covers rows (w*2+c)*16+(l>>2),
  //      granule l&3; pre-swizzled source granule = (l&3)^(d&3) ----
  const int gsrc = (l & 3) ^ ((l >> 2) & 3);
  const u16* whtB = WhT + ((size_t)b << 18);
  const u16* srcB0 = whtB + (size_t)((w * 2 + 0) * 16 + (l >> 2)) * 2048
                   + jq * 512 + gsrc * 8;
  const u16* srcB1 = whtB + (size_t)((w * 2 + 1) * 16 + (l >> 2)) * 2048
                   + jq * 512 + gsrc * 8;

  // ---- P producer constants (4 exps/thread/step) ----
  const int prow = tid >> 3, hg = tid & 7;        // row 0..31, 4-j group 0..7
  const float sSp = eSrc[(b << 11) + i0 + prow];
  const float* eDb = eDst + (b << 11) + jq * 512 + hg * 4;
  const uint32_t* adjB = adjBits + (size_t)(i0 + prow) * 64 + jq * 16;
  const int pOff = prow * 64 + (((hg >> 1) ^ (prow & 3)) * 16) + (hg & 1) * 8;
  float dsum = 0.f;

  // ---- consumer LDS offsets (bytes); row&3 == ln&3 for all our rows ----
  const int swz = (quad ^ (ln & 3)) * 16;
  const int aOff = (s * 16 + ln) * 64 + swz;
  const int bOff0 = (dh * 64 + 0 * 16 + ln) * 64 + swz;
  const int bOff1 = (dh * 64 + 1 * 16 + ln) * 64 + swz;
  const int bOff2 = (dh * 64 + 2 * 16 + ln) * 64 + swz;
  const int bOff3 = (dh * 64 + 3 * 16 + ln) * 64 + swz;

  f32x4 acc[4];
#pragma unroll
  for (int t = 0; t < 4; ++t) acc[t] = (f32x4){0.f, 0.f, 0.f, 0.f};

  // produce P tile (masked exp, bf16), accumulate bf16-rounded row-sum
#define PPROD(dv, aw, pdst) {                                                 \
    uint32_t nib = ((aw) >> (hg * 4)) & 0xfu;                                 \
    float x0 = sSp + (dv)[0], x1 = sSp + (dv)[1];                             \
    float x2 = sSp + (dv)[2], x3 = sSp + (dv)[3];                             \
    float p0 = exp2f(__builtin_amdgcn_fmed3f(x0, ALPHA * x0, 80.f));          \
    float p1 = exp2f(__builtin_amdgcn_fmed3f(x1, ALPHA * x1, 80.f));          \
    float p2 = exp2f(__builtin_amdgcn_fmed3f(x2, ALPHA * x2, 80.f));          \
    float p3 = exp2f(__builtin_amdgcn_fmed3f(x3, ALPHA * x3, 80.f));          \
    p0 = (nib & 1u) ? p0 : 0.f;                                               \
    p1 = (nib & 2u) ? p1 : 0.f;                                               \
    p2 = (nib & 4u) ? p2 : 0.f;                                               \
    p3 = (nib & 8u) ? p3 : 0.f;                                               \
    uint32_t w0 = pk2bf(p0, p1), w1 = pk2bf(p2, p3);                          \
    dsum += __uint_as_float(w0 << 16) + __uint_as_float(w0 & 0xffff0000u)     \
          + __uint_as_float(w1 << 16) + __uint_as_float(w1 & 0xffff0000u);    \
    *(uint2*)((char*)(pdst) + pOff) = make_uint2(w0, w1);                     \
  }

#define CONSUME(pPc, pBc) {                                                   \
    s16x8 af = *(const s16x8*)((const char*)(pPc) + aOff);                    \
    s16x8 b0 = *(const s16x8*)((const char*)(pBc) + bOff0);                   \
    s16x8 b1 = *(const s16x8*)((const char*)(pBc) + bOff1);                   \
    s16x8 b2 = *(const s16x8*)((const char*)(pBc) + bOff2);                   \
    s16x8 b3 = *(const s16x8*)((const char*)(pBc) + bOff3);                   \
    __builtin_amdgcn_s_setprio(1);                                            \
    acc[0] = __builtin_amdgcn_mfma_f32_16x16x32_bf16(af, b0, acc[0], 0, 0, 0);\
    acc[1] = __builtin_amdgcn_mfma_f32_16x16x32_bf16(af, b1, acc[1], 0, 0, 0);\
    acc[2] = __builtin_amdgcn_mfma_f32_16x16x32_bf16(af, b2, acc[2], 0, 0, 0);\
    acc[3] = __builtin_amdgcn_mfma_f32_16x16x32_bf16(af, b3, acc[3], 0, 0, 0);\
    __builtin_amdgcn_s_setprio(0);                                            \
  }

  u16 *bBc = bufB[0], *bBn = bufB[1];
  u16 *bPc = bufP[0], *bPn = bufP[1];

  // ---- prologue: produce P0, prefetch I1 into regs, stage B0 ----
  f32x4 dv = *(const f32x4*)(eDb);
  uint32_t aw = adjB[0];
  PPROD(dv, aw, bPc);
  dv = *(const f32x4*)(eDb + 32);
  aw = adjB[1];
  gl2lds16(srcB0, bBc + (w * 2 + 0) * 512);
  gl2lds16(srcB1, bBc + (w * 2 + 1) * 512);
  __syncthreads();

  for (int t = 0; t < 16; ++t) {
    if (t + 1 < 16) {
      // stage B(t+1)
      gl2lds16(srcB0 + (size_t)(t + 1) * 32, bBn + (w * 2 + 0) * 512);
      gl2lds16(srcB1 + (size_t)(t + 1) * 32, bBn + (w * 2 + 1) * 512);
      // produce P(t+1) from prefetched regs
      PPROD(dv, aw, bPn);
      if (t + 2 < 16) {            // prefetch I(t+2)
        dv = *(const f32x4*)(eDb + (t + 2) * 32);
        aw = adjB[t + 2];
      }
    }
    CONSUME(bPc, bBc);
    __syncthreads();               // next B staged + next P written; cur reads done
    u16* tb = bBc; bBc = bBn; bBn = tb;
    u16* tp = bPc; bPc = bPn; bPn = tp;
  }

  // ---- epilogue: write f32 partial numerator + denominator ----
  {
    // den: reduce dsum across the 8 hg-lanes of each row
#pragma unroll
    for (int m = 1; m < 8; m <<= 1) dsum += __shfl_xor(dsum, m);
    if ((tid & 7) == 0)
      denP[jq * 16384 + (b << 11) + i0 + prow] = dsum;

    float* np = numP + ((size_t)jq << 21)
              + ((size_t)((b << 11) + i0 + s * 16 + quad * 4) << 7)
              + dh * 64 + ln;
#pragma unroll
    for (int tt = 0; tt < 4; ++tt)
#pragma unroll
      for (int r = 0; r < 4; ++r)
        np[r * 128 + tt * 16] = acc[tt][r];
  }
#undef PPROD
#undef CONSUME
}

// ---------------- kernel 3: merge j-quarters, normalize, cast -------------
__global__ __launch_bounds__(256) void k_merge(
    const float* __restrict__ numP, const float* __restrict__ denP,
    const int* __restrict__ flag, void* __restrict__ outV) {
  const int gid = blockIdx.x * 256 + threadIdx.x;
  const int e0 = gid * 8;           // 8 floats, same output row (128 | 8)
  const int row = e0 >> 7;

  f32x4 v0 = (f32x4){0.f, 0.f, 0.f, 0.f};
  f32x4 v1 = (f32x4){0.f, 0.f, 0.f, 0.f};
  float ds = 0.f;
#pragma unroll
  for (int q = 0; q < 4; ++q) {
    v0 += *(const f32x4*)(numP + ((size_t)q << 21) + e0);
    v1 += *(const f32x4*)(numP + ((size_t)q << 21) + e0 + 4);
    ds += denP[q * 16384 + row];
  }
  float inv = 1.0f / fmaxf(ds, 1e-37f);
  v0 *= inv;
  v1 *= inv;

  if (*flag) {
    uint4 pk = make_uint4(pk2bf(v0[0], v0[1]), pk2bf(v0[2], v0[3]),
                          pk2bf(v1[0], v1[1]), pk2bf(v1[2], v1[3]));
    *(uint4*)((u16*)outV + e0) = pk;
  } else {
    *(f32x4*)((float*)outV + e0) = v0;
    *(f32x4*)((float*)outV + e0 + 4) = v1;
  }
}

extern "C" void kernel_launch(void* const* d_in, const int* in_sizes, int n_in,
                              void* d_out, int out_size, void* d_ws, size_t ws_size,
                              hipStream_t stream) {
  const void* h   = d_in[0];
  const int* adj  = (const int*)d_in[1];
  const void* Wg  = d_in[2];
  const void* aS  = d_in[3];
  const void* aD  = d_in[4];

  const size_t OFF_ES   = (size_t)4 << 20;               // 4 MB WhT
  const size_t OFF_ED   = OFF_ES + (64 << 10);
  const size_t OFF_BITS = OFF_ED + (64 << 10);
  const size_t OFF_FLAG = OFF_BITS + (512 << 10);
  const size_t OFF_NUM  = (size_t)5 << 20;               // 4 x 8 MB f32 partial num
  const size_t OFF_DEN  = (size_t)40 << 20;              // 4 x 64 KB f32 partial den
  const size_t NEEDED   = OFF_DEN + (256 << 10);

  if (ws_size < NEEDED) {
    int n32 = out_size / 2;
    k_zero<<<(n32 + 255) / 256, 256, 0, stream>>>((uint32_t*)d_out, n32);
    return;
  }

  char* ws = (char*)d_ws;
  u16* WhT      = (u16*)ws;
  float* eSp    = (float*)(ws + OFF_ES);
  float* eDp    = (float*)(ws + OFF_ED);
  uint32_t* bit = (uint32_t*)(ws + OFF_BITS);
  int* flag     = (int*)(ws + OFF_FLAG);
  float* numP   = (float*)(ws + OFF_NUM);
  float* denP   = (float*)(ws + OFF_DEN);

  k_pack_adj<<<2048, 256, 0, stream>>>(adj, bit, (const u16*)h, flag);
  k_wh<<<256, 256, 0, stream>>>(h, Wg, aS, aD, flag, WhT, eSp, eDp);
  k_attn<<<2048, 256, 0, stream>>>(WhT, eSp, eDp, bit, numP, denP);
  k_merge<<<1024, 256, 0, stream>>>(numP, denP, flag, d_out);
}

// Round 8
// 116.225 us; speedup vs baseline: 1.1243x; 1.0969x over previous
//
#include <hip/hip_runtime.h>
#include <stdint.h>

#define ALPHA 0.2f
#define LOG2E 1.4426950408889634f

typedef unsigned short u16;
typedef short s16x8 __attribute__((ext_vector_type(8)));   // 8 bf16 as shorts
typedef float f32x4 __attribute__((ext_vector_type(4)));

union BF8 { s16x8 v; uint32_t u[4]; u16 s[8]; uint4 q; };

static __device__ __forceinline__ float bf2f(u16 u) {
  union { uint32_t i; float f; } c; c.i = ((uint32_t)u) << 16; return c.f;
}
// round-to-nearest pack of two f32 -> packed bf16x2
static __device__ __forceinline__ uint32_t pk2bf(float lo, float hi) {
  uint32_t ul = __float_as_uint(lo) + 0x8000u;
  uint32_t uh = __float_as_uint(hi) + 0x8000u;
  return (ul >> 16) | (uh & 0xffff0000u);
}

// async global->LDS, 16B per lane; lds dest must be wave-uniform base
static __device__ __forceinline__ void gl2lds16(const void* g, void* l) {
  __builtin_amdgcn_global_load_lds(
      (const __attribute__((address_space(1))) uint32_t*)g,
      (__attribute__((address_space(3))) uint32_t*)l, 16, 0, 0);
}

// ------------- fallback: ws too small -> zero output (diagnostic) --------
__global__ __launch_bounds__(256) void k_zero(uint32_t* __restrict__ out, int n32) {
  int gid = blockIdx.x * 256 + threadIdx.x;
  if (gid < n32) out[gid] = 0u;
}

// ---------------- kernel 1 (fused, wh-FIRST): Wh GEMM + adj-pack ----------
// blocks 0..255: WhT = (h@W)^T (64 rows each, R2-identical internals) +
//                e_src/e_dst. Dispatched FIRST (critical path).
// blocks 256..2303: pack adj -> bitmask (block 256 writes dtype flag).
//                Memory-bound; backfills CU slots while wh runs.
// WhT: [8][128][2048] bf16 ; eS/eD: [8][2048] f32 (pre-scaled by log2e)
__global__ __launch_bounds__(256) void k_prep(
    const int* __restrict__ adj, uint32_t* __restrict__ bits,
    const void* __restrict__ hV, const void* __restrict__ WgV,
    const void* __restrict__ aSrcV, const void* __restrict__ aDstV,
    int* __restrict__ flag,
    u16* __restrict__ WhT, float* __restrict__ eS, float* __restrict__ eD) {
  __shared__ __align__(16) char smemRaw[34816];    // WT bf16[128][136] then f32 tile[64][130]
  __shared__ float aS[128], aD[128];

  const int tid = threadIdx.x;
  const int bk = blockIdx.x;

  if (bk >= 256) {            // ---------------- pack role ----------------
    const int pk = bk - 256;
    int base = pk * 256 + tid;
#pragma unroll
    for (int it = 0; it < 8; ++it) {
      int gid = base + it * (2048 * 256);
      unsigned long long m = __ballot(adj[gid] != 0);
      if ((tid & 63) == 0)
        *(unsigned long long*)(&bits[gid >> 5]) = m;
    }
    if (pk == 0 && tid < 64) {   // dtype vote (1=bf16, 0=fp32) for k_attn
      u16 v = ((const u16*)hV)[2 * tid];
      int e = (v >> 7) & 0xff;
      unsigned long long dm = __ballot(e >= 100 && e <= 140);
      if (tid == 0) flag[0] = (__popcll(dm) >= 48) ? 1 : 0;
    }
    return;
  }

  // ---------------- wh role: 64 rows per block (R2 internals) ------------
  u16*   WT   = (u16*)smemRaw;
  float* tile = (float*)smemRaw;
  const int mb = bk * 64;

  // wave-local dtype vote (flag not written yet; identical result per wave)
  int isBf;
  {
    u16 v = ((const u16*)hV)[2 * (tid & 63)];
    int e = (v >> 7) & 0xff;
    unsigned long long dm = __ballot(e >= 100 && e <= 140);
    isBf = (__popcll(dm) >= 48) ? 1 : 0;
  }

  if (isBf) {
    const u16* Wg = (const u16*)WgV;
    for (int it = 0; it < 8; ++it) {
      int idx = tid + it * 256;
      int k = idx >> 4, c0 = (idx & 15) * 8;
      uint4 w4 = *(const uint4*)(Wg + (k << 7) + c0);
      u16* wsv = (u16*)&w4;
#pragma unroll
      for (int e = 0; e < 8; ++e) WT[(c0 + e) * 136 + k] = wsv[e];
    }
    if (tid < 128) aS[tid] = bf2f(((const u16*)aSrcV)[tid]);
    else           aD[tid - 128] = bf2f(((const u16*)aDstV)[tid - 128]);
  } else {
    const float* Wg = (const float*)WgV;
    for (int it = 0; it < 8; ++it) {
      int idx = tid + it * 256;
      int k = idx >> 4, c0 = (idx & 15) * 8;
      float4 w0 = *(const float4*)(Wg + (k << 7) + c0);
      float4 w1 = *(const float4*)(Wg + (k << 7) + c0 + 4);
      float wf[8] = {w0.x, w0.y, w0.z, w0.w, w1.x, w1.y, w1.z, w1.w};
#pragma unroll
      for (int e = 0; e < 8; ++e)
        WT[(c0 + e) * 136 + k] = (u16)((__float_as_uint(wf[e]) + 0x8000u) >> 16);
    }
    if (tid < 128) aS[tid] = ((const float*)aSrcV)[tid];
    else           aD[tid - 128] = ((const float*)aDstV)[tid - 128];
  }
  __syncthreads();

  const int wv = tid >> 6, lane = tid & 63, ln = lane & 15, quad = lane >> 4;
  const int row = mb + wv * 16 + ln;

  f32x4 acc[8];
#pragma unroll
  for (int t = 0; t < 8; ++t) acc[t] = (f32x4){0.f, 0.f, 0.f, 0.f};

  if (isBf) {
    const u16* h = (const u16*)hV;
#pragma unroll
    for (int ks = 0; ks < 4; ++ks) {
      s16x8 af = *(const s16x8*)(h + (row << 7) + ks * 32 + quad * 8);
#pragma unroll
      for (int t = 0; t < 8; ++t) {
        s16x8 bfg = *(const s16x8*)(&WT[(t * 16 + ln) * 136 + ks * 32 + quad * 8]);
        acc[t] = __builtin_amdgcn_mfma_f32_16x16x32_bf16(af, bfg, acc[t], 0, 0, 0);
      }
    }
  } else {
    const float* h = (const float*)hV;
#pragma unroll
    for (int ks = 0; ks < 4; ++ks) {
      float4 a0 = *(const float4*)(h + (row << 7) + ks * 32 + quad * 8);
      float4 a1 = *(const float4*)(h + (row << 7) + ks * 32 + quad * 8 + 4);
      BF8 af;
      af.u[0] = pk2bf(a0.x, a0.y);
      af.u[1] = pk2bf(a0.z, a0.w);
      af.u[2] = pk2bf(a1.x, a1.y);
      af.u[3] = pk2bf(a1.z, a1.w);
#pragma unroll
      for (int t = 0; t < 8; ++t) {
        s16x8 bfg = *(const s16x8*)(&WT[(t * 16 + ln) * 136 + ks * 32 + quad * 8]);
        acc[t] = __builtin_amdgcn_mfma_f32_16x16x32_bf16(af.v, bfg, acc[t], 0, 0, 0);
      }
    }
  }
  __syncthreads();                                   // done with WT; reuse as tile

  // D layout: row = quad*4+r, col = t*16+ln
#pragma unroll
  for (int t = 0; t < 8; ++t)
#pragma unroll
    for (int r = 0; r < 4; ++r)
      tile[(wv * 16 + quad * 4 + r) * 130 + t * 16 + ln] = acc[t][r];
  __syncthreads();

  if (tid < 128) {
    int r = tid & 63, grp = tid >> 6;
    const float* a = grp ? aD : aS;
    float sum = 0.f;
#pragma unroll 4
    for (int d = 0; d < 128; ++d) sum += tile[r * 130 + d] * a[d];
    int m = mb + r, b = m >> 11, n = m & 2047;
    (grp ? eD : eS)[(b << 11) + n] = sum * LOG2E;
  }

  // write WhT[b][d][n] (transposed bf16), 64B per thread
  {
    int d = tid >> 1, half = tid & 1;
    int n0 = mb & 2047, b = mb >> 11;
    uint32_t pk[16];
#pragma unroll
    for (int qq = 0; qq < 16; ++qq) {
      float v0 = tile[(half * 32 + 2 * qq) * 130 + d];
      float v1 = tile[(half * 32 + 2 * qq + 1) * 130 + d];
      pk[qq] = pk2bf(v0, v1);
    }
    uint4* dst = (uint4*)(WhT + (size_t)((b << 7) + d) * 2048 + n0 + half * 32);
#pragma unroll
    for (int c = 0; c < 4; ++c)
      dst[c] = make_uint4(pk[c * 4], pk[c * 4 + 1], pk[c * 4 + 2], pk[c * 4 + 3]);
  }
}

// ---------------- kernel 2: masked softmax(rank-1 logits) @ Wh ------------
// UNCHANGED from round 2 (best measured total: 119.0 us).
// grid: 512 = b(8) x ig(64, 32 rows); block 512 thr = 8 waves.
__global__ __launch_bounds__(512, 4) void k_attn(
    const u16* __restrict__ WhT, const float* __restrict__ eSrc,
    const float* __restrict__ eDst, const uint32_t* __restrict__ adjBits,
    const int* __restrict__ flag, void* __restrict__ outV) {
  __shared__ __align__(16) u16 bufB[2][8192];   // 2 x 16KB  [128 d][64 j]
  __shared__ __align__(16) u16 bufP[2][2048];   // 2 x 4KB   [32 i][64 j]; den after loop

  const int tid = threadIdx.x;
  // XCD swizzle: 512 % 8 == 0, b == XCD id -> each XCD L2 holds one WhT[b]
  const int bid = (blockIdx.x & 7) * 64 + (blockIdx.x >> 3);
  const int b = bid >> 6, ig = bid & 63;
  const int i0 = ig * 32;

  const int w = tid >> 6, l = tid & 63;
  const int ln = l & 15, quad = l >> 4;
  const int s = w & 1, dh = w >> 1;

  // ---- staging constants (B tile) ----
  const int gsrc = (l & 7) ^ ((l >> 3) & 7);
  const u16* whtB = WhT + ((size_t)b << 18);
  const u16* srcB = whtB + (size_t)(w * 8 + (l >> 3)) * 2048 + gsrc * 8;

  // ---- P producer constants ----
  const int prow = tid >> 4, hg = tid & 15;       // row 0..31, 4-j group 0..15
  const float sSp = eSrc[(b << 11) + i0 + prow];
  const float* eDb = eDst + (b << 11) + hg * 4;
  const uint32_t* adjB = adjBits + (size_t)(i0 + prow) * 64 + (hg >> 3);
  const int pOff = prow * 128 + ((hg ^ ((prow & 7) << 1)) * 8);   // bytes

  // ---- consumer LDS offsets (bytes) ----
  const int aOff0 = (s * 16 + ln) * 128 + (((0 * 4 + quad) ^ (ln & 7)) * 16);
  const int aOff1 = (s * 16 + ln) * 128 + (((1 * 4 + quad) ^ (ln & 7)) * 16);
  const int bOff00 = (dh * 32 + 0 * 16 + ln) * 128 + (((0 * 4 + quad) ^ (ln & 7)) * 16);
  const int bOff10 = (dh * 32 + 1 * 16 + ln) * 128 + (((0 * 4 + quad) ^ (ln & 7)) * 16);
  const int bOff01 = (dh * 32 + 0 * 16 + ln) * 128 + (((1 * 4 + quad) ^ (ln & 7)) * 16);
  const int bOff11 = (dh * 32 + 1 * 16 + ln) * 128 + (((1 * 4 + quad) ^ (ln & 7)) * 16);

  f32x4 acc0 = (f32x4){0.f, 0.f, 0.f, 0.f};
  f32x4 acc1 = (f32x4){0.f, 0.f, 0.f, 0.f};
  f32x4 accD = (f32x4){0.f, 0.f, 0.f, 0.f};

  BF8 ones;
  ones.u[0] = 0x3f803f80u; ones.u[1] = 0x3f803f80u;
  ones.u[2] = 0x3f803f80u; ones.u[3] = 0x3f803f80u;

#define PPROD(dv, aw, pdst)  {                                                \
    uint32_t nib = ((aw) >> ((hg & 7) * 4)) & 0xfu;                           \
    float x0 = sSp + (dv)[0], x1 = sSp + (dv)[1];                             \
    float x2 = sSp + (dv)[2], x3 = sSp + (dv)[3];                             \
    float p0 = exp2f(__builtin_amdgcn_fmed3f(x0, ALPHA * x0, 80.f));          \
    float p1 = exp2f(__builtin_amdgcn_fmed3f(x1, ALPHA * x1, 80.f));          \
    float p2 = exp2f(__builtin_amdgcn_fmed3f(x2, ALPHA * x2, 80.f));          \
    float p3 = exp2f(__builtin_amdgcn_fmed3f(x3, ALPHA * x3, 80.f));          \
    uint32_t m01 = ((nib & 1u) ? 0x0000ffffu : 0u) | ((nib & 2u) ? 0xffff0000u : 0u); \
    uint32_t m23 = ((nib & 4u) ? 0x0000ffffu : 0u) | ((nib & 8u) ? 0xffff0000u : 0u); \
    *(uint2*)((char*)(pdst) + pOff) = make_uint2(pk2bf(p0, p1) & m01,         \
                                                 pk2bf(p2, p3) & m23);        \
  }

#define CONSUME(pPc, pBc)  {                                                  \
    s16x8 af0 = *(const s16x8*)((const char*)(pPc) + aOff0);                  \
    s16x8 af1 = *(const s16x8*)((const char*)(pPc) + aOff1);                  \
    s16x8 b00 = *(const s16x8*)((const char*)(pBc) + bOff00);                 \
    s16x8 b10 = *(const s16x8*)((const char*)(pBc) + bOff10);                 \
    s16x8 b01 = *(const s16x8*)((const char*)(pBc) + bOff01);                 \
    s16x8 b11 = *(const s16x8*)((const char*)(pBc) + bOff11);                 \
    __builtin_amdgcn_s_setprio(1);                                            \
    acc0 = __builtin_amdgcn_mfma_f32_16x16x32_bf16(af0, b00, acc0, 0, 0, 0);  \
    acc1 = __builtin_amdgcn_mfma_f32_16x16x32_bf16(af0, b10, acc1, 0, 0, 0);  \
    acc0 = __builtin_amdgcn_mfma_f32_16x16x32_bf16(af1, b01, acc0, 0, 0, 0);  \
    acc1 = __builtin_amdgcn_mfma_f32_16x16x32_bf16(af1, b11, acc1, 0, 0, 0);  \
    if (dh == 0) {                                                            \
      accD = __builtin_amdgcn_mfma_f32_16x16x32_bf16(af0, ones.v, accD, 0, 0, 0); \
      accD = __builtin_amdgcn_mfma_f32_16x16x32_bf16(af1, ones.v, accD, 0, 0, 0); \
    }                                                                         \
    __builtin_amdgcn_s_setprio(0);                                            \
  }

  u16 *bBc = bufB[0], *bBn = bufB[1];
  u16 *bPc = bufP[0], *bPn = bufP[1];

  // ---- prologue: stage tile 0 + produce P0 ----
  gl2lds16(srcB, bBc + w * 512);
  gl2lds16(srcB + 131072, bBc + 4096 + w * 512);
  {
    f32x4 dv = *(const f32x4*)(eDb);
    uint32_t aw = adjB[0];
    PPROD(dv, aw, bPc);
  }
  __syncthreads();

  for (int t = 0; t < 32; ++t) {
    if (t + 1 < 32) {
      // stage B[t+1]
      gl2lds16(srcB + (size_t)(t + 1) * 64, bBn + w * 512);
      gl2lds16(srcB + (size_t)(t + 1) * 64 + 131072, bBn + 4096 + w * 512);
      // compute P[t+1]
      f32x4 dv = *(const f32x4*)(eDb + (t + 1) * 64);
      uint32_t aw = adjB[(t + 1) * 2];
      PPROD(dv, aw, bPn);
    }
    CONSUME(bPc, bBc);
    __syncthreads();          // next buffers complete; cur reads done
    u16* tb = bBc; bBc = bBn; bBn = tb;
    u16* tp = bPc; bPc = bPn; bPn = tp;
  }

  // ---- epilogue: share denominators via LDS (reuse bufP), normalize ----
  float* den = (float*)bufP;
  if (dh == 0 && ln == 0) {
#pragma unroll
    for (int r = 0; r < 4; ++r) den[s * 16 + quad * 4 + r] = accD[r];
  }
  __syncthreads();

  float inv[4];
#pragma unroll
  for (int r = 0; r < 4; ++r)
    inv[r] = 1.0f / fmaxf(den[s * 16 + quad * 4 + r], 1e-37f);

  const int isBf = *flag;
  if (isBf) {
    u16* outp = (u16*)outV;
#pragma unroll
    for (int tt = 0; tt < 2; ++tt) {
      f32x4 a = tt ? acc1 : acc0;
#pragma unroll
      for (int r = 0; r < 4; ++r) {
        size_t off = ((size_t)((b << 11) + i0 + s * 16 + quad * 4 + r) << 7)
                   + dh * 32 + tt * 16 + ln;
        float v = a[r] * inv[r];
        outp[off] = (u16)((__float_as_uint(v) + 0x8000u) >> 16);
      }
    }
  } else {
    float* outp = (float*)outV;
#pragma unroll
    for (int tt = 0; tt < 2; ++tt) {
      f32x4 a = tt ? acc1 : acc0;
#pragma unroll
      for (int r = 0; r < 4; ++r) {
        size_t off = ((size_t)((b << 11) + i0 + s * 16 + quad * 4 + r) << 7)
                   + dh * 32 + tt * 16 + ln;
        outp[off] = a[r] * inv[r];
      }
    }
  }
#undef PPROD
#undef CONSUME
}

extern "C" void kernel_launch(void* const* d_in, const int* in_sizes, int n_in,
                              void* d_out, int out_size, void* d_ws, size_t ws_size,
                              hipStream_t stream) {
  const void* h   = d_in[0];
  const int* adj  = (const int*)d_in[1];
  const void* Wg  = d_in[2];
  const void* aS  = d_in[3];
  const void* aD  = d_in[4];

  const size_t OFF_ES   = (size_t)4 << 20;               // 4 MB WhT
  const size_t OFF_ED   = OFF_ES + (64 << 10);
  const size_t OFF_BITS = OFF_ED + (64 << 10);
  const size_t OFF_FLAG = OFF_BITS + (512 << 10);
  const size_t NEEDED   = OFF_FLAG + 64;

  if (ws_size < NEEDED) {
    int n32 = out_size / 2;
    k_zero<<<(n32 + 255) / 256, 256, 0, stream>>>((uint32_t*)d_out, n32);
    return;
  }

  char* ws = (char*)d_ws;
  u16* WhT      = (u16*)ws;
  float* eSp    = (float*)(ws + OFF_ES);
  float* eDp    = (float*)(ws + OFF_ED);
  uint32_t* bit = (uint32_t*)(ws + OFF_BITS);
  int* flag     = (int*)(ws + OFF_FLAG);

  // wh role first (blocks 0..255, critical path), pack backfills (256..2303)
  k_prep<<<2304, 256, 0, stream>>>(adj, bit, h, Wg, aS, aD, flag, WhT, eSp, eDp);
  k_attn<<<512, 512, 0, stream>>>(WhT, eSp, eDp, bit, flag, d_out);
}